// Round 5
// baseline (715.632 us; speedup 1.0000x reference)
//
#include <hip/hip_runtime.h>

// ---------------------------------------------------------------------------
// MistralAttention on MI355X (gfx950), bf16-internal compute.
// cast f32->bf16 -> QKV GEMM (32x32x16 MFMA, BK=64, 128x256 block, 64x128
// wave tile) -> RoPE(K) -> causal GQA flash attention (paired q-tiles,
// pipelined, no-max softmax) -> O-proj GEMM -> f32.
// Workspace layout (128 MiB):
//   [0,          50331648)  Wqkv bf16  -> later AttnOut bf16
//   [50331648,   83886080)  X bf16     -> later Wo bf16
//   [83886080,  134217728)  QKV bf16 (K RoPE'd in place; Q roped in-register)
// ---------------------------------------------------------------------------

typedef short bf16x8 __attribute__((ext_vector_type(8)));   // 8 bf16 = 4 VGPR
typedef short bf16x4 __attribute__((ext_vector_type(4)));
typedef float floatx4 __attribute__((ext_vector_type(4)));
typedef float floatx16 __attribute__((ext_vector_type(16)));
typedef unsigned short u16x4 __attribute__((ext_vector_type(4)));

__device__ __forceinline__ unsigned short f2bf(float f) {   // RNE f32->bf16
  unsigned u = __float_as_uint(f);
  u += 0x7FFFu + ((u >> 16) & 1u);
  return (unsigned short)(u >> 16);
}
__device__ __forceinline__ float bf2f(unsigned short h) {
  return __uint_as_float(((unsigned)h) << 16);
}

// async global->LDS, 16B/lane; dest is wave-uniform base + lane*16 (m104).
__device__ __forceinline__ void async16(const void* g, void* l) {
  __builtin_amdgcn_global_load_lds(
      (const __attribute__((address_space(1))) unsigned int*)g,
      (__attribute__((address_space(3))) unsigned int*)l, 16, 0, 0);
}

// ---------------------------------------------------------------------------
__global__ void cvt_f32_bf16(const float4* __restrict__ in,
                             u16x4* __restrict__ out, int n4) {
  int i = blockIdx.x * 256 + threadIdx.x;
  if (i < n4) {
    float4 v = in[i];
    u16x4 o;
    o.x = f2bf(v.x); o.y = f2bf(v.y); o.z = f2bf(v.z); o.w = f2bf(v.w);
    out[i] = o;
  }
}

// ---------------------------------------------------------------------------
// NT GEMM: C[M][N] = A[M][K] * B[N][K]^T, bf16 in, fp32 acc.
// Round-5: 128x256 block tile, BK=64 (48 KB LDS), 4 waves as 2(M)x2(N),
// wave tile 64x128 = 2x4 of v_mfma_f32_32x32x16_bf16. Fragment reads per
// wave-iter: 8 A + 16 B = 24 ds_read_b128 feeding 32 MFMAs (0.75 reads/MFMA
// vs 1.0 in the 2x2 tile) -- LDS read BW is the measured binding pipe
// (R4: MfmaUtil 41%, VALUBusy 15%). Source-XOR-swizzled staging as before.
// acc = 128 VGPR; __launch_bounds__(256,2) -> 2 waves/SIMD.
// ---------------------------------------------------------------------------
template <int OUT_BF16>
__global__ __launch_bounds__(256, 2) void gemm_bt_w(
    const unsigned short* __restrict__ A, const unsigned short* __restrict__ B,
    void* __restrict__ Cout, int M, int N, int K) {
  __shared__ __align__(16) unsigned short As[128 * 64];   // 16 KB
  __shared__ __align__(16) unsigned short Bs[256 * 64];   // 32 KB
  const int tid = threadIdx.x;
  const int wave = tid >> 6, lane = tid & 63;
  const int l32 = lane & 31, hi = lane >> 5;
  const int bm = blockIdx.y << 7, bn = blockIdx.x << 8;
  const int wm = (wave >> 1) << 6;      // 2 waves in M: 0,64
  const int wn = (wave & 1) << 7;       // 2 waves in N: 0,128

  floatx16 acc[2][4];
#pragma unroll
  for (int mi = 0; mi < 2; ++mi)
#pragma unroll
    for (int ni = 0; ni < 4; ++ni)
#pragma unroll
      for (int r = 0; r < 16; ++r) acc[mi][ni][r] = 0.f;

  // staging: 1KB block covers 8 rows x 64 k; lane -> row lane>>3 within blk,
  // phys chunk lane&7 holds logical chunk (lane&7)^(row&7) [source-swizzled]
  const int srow = lane >> 3;
  const int schunk = (lane & 7) ^ srow;
  const unsigned short* Asrc[4];
  const unsigned short* Bsrc[8];
  char* lA[4];
  char* lB[8];
#pragma unroll
  for (int j = 0; j < 4; ++j) {   // A: 16 blocks of 8 rows, 4 per wave
    int blk = wave + 4 * j;
    Asrc[j] = A + (size_t)(bm + blk * 8 + srow) * K + schunk * 8;
    lA[j] = (char*)As + blk * 1024;
  }
#pragma unroll
  for (int j = 0; j < 8; ++j) {   // B: 32 blocks of 8 rows, 8 per wave
    int blk = wave + 4 * j;
    Bsrc[j] = B + (size_t)(bn + blk * 8 + srow) * K + schunk * 8;
    lB[j] = (char*)Bs + blk * 1024;
  }

  // fragment bases; phys chunk = (kstep*2+hi) ^ (row&7), row&7 = l32&7
  const unsigned short* Ap = As + (wm + l32) * 64;
  const unsigned short* Bp = Bs + (wn + l32) * 64;
  int co[4];
#pragma unroll
  for (int k = 0; k < 4; ++k) co[k] = ((k * 2 + hi) ^ (l32 & 7)) * 8;

  for (int k0 = 0; k0 < K; k0 += 64) {
    __syncthreads();
#pragma unroll
    for (int j = 0; j < 4; ++j) async16(Asrc[j] + k0, lA[j]);
#pragma unroll
    for (int j = 0; j < 8; ++j) async16(Bsrc[j] + k0, lB[j]);
    __syncthreads();
#pragma unroll
    for (int k = 0; k < 4; ++k) {
      bf16x8 af[2], bfr[4];
#pragma unroll
      for (int mi = 0; mi < 2; ++mi)
        af[mi] = *(const bf16x8*)(Ap + mi * 2048 + co[k]);
#pragma unroll
      for (int ni = 0; ni < 4; ++ni)
        bfr[ni] = *(const bf16x8*)(Bp + ni * 2048 + co[k]);
#pragma unroll
      for (int mi = 0; mi < 2; ++mi)
#pragma unroll
        for (int ni = 0; ni < 4; ++ni)
          acc[mi][ni] = __builtin_amdgcn_mfma_f32_32x32x16_bf16(
              af[mi], bfr[ni], acc[mi][ni], 0, 0, 0);
    }
  }

  // C/D layout (m74/m101): col = lane&31, row = (reg&3)+8*(reg>>2)+4*(lane>>5)
#pragma unroll
  for (int mi = 0; mi < 2; ++mi)
#pragma unroll
    for (int ni = 0; ni < 4; ++ni)
#pragma unroll
      for (int reg = 0; reg < 16; ++reg) {
        int row = bm + wm + mi * 32 + 4 * hi + (reg & 3) + 8 * (reg >> 2);
        int col = bn + wn + ni * 32 + l32;
        if (OUT_BF16)
          ((unsigned short*)Cout)[(size_t)row * N + col] = f2bf(acc[mi][ni][reg]);
        else
          ((float*)Cout)[(size_t)row * N + col] = acc[mi][ni][reg];
      }
}

// ---------------------------------------------------------------------------
// RoPE in place on K heads (slots 32..39 of QKV [4096][6144]).
// ---------------------------------------------------------------------------
__global__ void rope_k_kernel(unsigned short* __restrict__ qkv) {
  const int t = blockIdx.x;
  const int s = t & 1023;
  const int head = 32 + blockIdx.y * 4 + (threadIdx.x >> 6);
  const int d = threadIdx.x & 63;
  unsigned short* p = qkv + (size_t)t * 6144 + head * 128;
  float x1 = bf2f(p[d]), x2 = bf2f(p[d + 64]);
  float inv_freq = exp2f((float)d * -0.20762050593046015f);
  float ang = (float)s * inv_freq;
  float c, sn;
  __sincosf(ang, &sn, &c);
  p[d] = f2bf(x1 * c - x2 * sn);
  p[d + 64] = f2bf(x2 * c + x1 * sn);
}

// ---------------------------------------------------------------------------
// Causal GQA flash attention, paired q-tiles (uniform 17 iters/block).
// 4 waves x 16 q-rows; register-double-buffered K/V staging; no-max softmax;
// scale folded into Q; RoPE(Q) fused. Unchanged from round 4.
// ---------------------------------------------------------------------------
__global__ __launch_bounds__(256, 3) void flash_attn(
    const unsigned short* __restrict__ qkv, unsigned short* __restrict__ aout) {
  const int pr = blockIdx.x;  // 0..7
  const int h = blockIdx.y, b = blockIdx.z;
  const int kh = h >> 2;
  const int tid = threadIdx.x;
  const int wave = tid >> 6, lane = tid & 63;
  const int quad = lane >> 4, l16 = lane & 15;

  __shared__ __align__(16) unsigned short Ks[64][136];
  __shared__ __align__(16) unsigned short Vt[128][68];
  __shared__ __align__(16) unsigned short Ps[64][68];

  const int krow = tid >> 4, kcol = (tid & 15) << 3;
  const int vrb = (tid & 15) << 2, vcol = (tid >> 4) << 3;
  const unsigned short* kp = qkv + (size_t)(b << 10) * 6144 + 4096 + kh * 128;
  const unsigned short* vp = qkv + (size_t)(b << 10) * 6144 + 5120 + kh * 128;

  for (int half = 0; half < 2; ++half) {
    const int qt = half ? pr : 15 - pr;  // heavy tile first
    const int q0 = qt << 6;

    bf16x8 qf[4];
    {
      const int qrow = q0 + wave * 16 + l16;
      const unsigned short* qp =
          qkv + (size_t)((b << 10) + qrow) * 6144 + h * 128 + quad * 8;
#pragma unroll
      for (int ks = 0; ks < 4; ++ks) qf[ks] = *(const bf16x8*)(qp + ks * 32);
      const float pos = (float)qrow;
      const float scale = 0.08838834764831845f;  // 128^-0.5
#pragma unroll
      for (int ks = 0; ks < 2; ++ks)
#pragma unroll
        for (int e = 0; e < 8; ++e) {
          int d = ks * 32 + quad * 8 + e;
          float ang = pos * exp2f((float)d * -0.20762050593046015f);
          float c, sn;
          __sincosf(ang, &sn, &c);
          float x1 = bf2f((unsigned short)qf[ks][e]);
          float x2 = bf2f((unsigned short)qf[ks + 2][e]);
          qf[ks][e] = (short)f2bf((x1 * c - x2 * sn) * scale);
          qf[ks + 2][e] = (short)f2bf((x2 * c + x1 * sn) * scale);
        }
    }

    floatx4 o_acc[8];
#pragma unroll
    for (int i = 0; i < 8; ++i) o_acc[i] = (floatx4){0.f, 0.f, 0.f, 0.f};
    float l_lane[4] = {0.f, 0.f, 0.f, 0.f};

    bf16x8 kreg[4], vreg[4];
#pragma unroll
    for (int j = 0; j < 4; ++j)
      kreg[j] = *(const bf16x8*)(kp + (size_t)(krow + j * 16) * 6144 + kcol);
#pragma unroll
    for (int j = 0; j < 4; ++j)
      vreg[j] = *(const bf16x8*)(vp + (size_t)(vrb + j) * 6144 + vcol);

    for (int t = 0; t <= qt; ++t) {
      __syncthreads();
#pragma unroll
      for (int j = 0; j < 4; ++j)
        *(bf16x8*)&Ks[krow + j * 16][kcol] = kreg[j];
#pragma unroll
      for (int e = 0; e < 8; ++e) {
        bf16x4 w = {vreg[0][e], vreg[1][e], vreg[2][e], vreg[3][e]};
        *(bf16x4*)&Vt[vcol + e][vrb] = w;
      }
      __syncthreads();
      if (t < qt) {
        const size_t nb = (size_t)((t + 1) << 6) * 6144;
#pragma unroll
        for (int j = 0; j < 4; ++j)
          kreg[j] =
              *(const bf16x8*)(kp + nb + (size_t)(krow + j * 16) * 6144 + kcol);
#pragma unroll
        for (int j = 0; j < 4; ++j)
          vreg[j] = *(const bf16x8*)(vp + nb + (size_t)(vrb + j) * 6144 + vcol);
      }

      floatx4 sacc[4];
#pragma unroll
      for (int ni = 0; ni < 4; ++ni) sacc[ni] = (floatx4){0.f, 0.f, 0.f, 0.f};
#pragma unroll
      for (int ks = 0; ks < 4; ++ks)
#pragma unroll
        for (int ni = 0; ni < 4; ++ni) {
          bf16x8 kf = *(const bf16x8*)&Ks[ni * 16 + l16][ks * 32 + quad * 8];
          sacc[ni] = __builtin_amdgcn_mfma_f32_16x16x32_bf16(qf[ks], kf,
                                                             sacc[ni], 0, 0, 0);
        }

      const bool masked = (t == qt);
#pragma unroll
      for (int r = 0; r < 4; ++r) {
        float rs = 0.f;
#pragma unroll
        for (int ni = 0; ni < 4; ++ni) {
          float e = __expf(sacc[ni][r]);
          if (masked && (ni * 16 + l16) > (wave * 16 + quad * 4 + r)) e = 0.f;
          rs += e;
          Ps[wave * 16 + quad * 4 + r][ni * 16 + l16] = f2bf(e);
        }
        l_lane[r] += rs;
      }
      asm volatile("s_waitcnt lgkmcnt(0)" ::: "memory");  // Ps wave-private

#pragma unroll
      for (int ks2 = 0; ks2 < 2; ++ks2) {
        bf16x8 pf = *(const bf16x8*)&Ps[wave * 16 + l16][ks2 * 32 + quad * 8];
#pragma unroll
        for (int n8 = 0; n8 < 8; ++n8) {
          bf16x8 vf = *(const bf16x8*)&Vt[n8 * 16 + l16][ks2 * 32 + quad * 8];
          o_acc[n8] = __builtin_amdgcn_mfma_f32_16x16x32_bf16(pf, vf, o_acc[n8],
                                                              0, 0, 0);
        }
      }
    }

#pragma unroll
    for (int r = 0; r < 4; ++r) {
      float l = l_lane[r];
#pragma unroll
      for (int off = 1; off < 16; off <<= 1) l += __shfl_xor(l, off, 64);
      float inv = 1.0f / l;
      int row = q0 + wave * 16 + quad * 4 + r;
      unsigned short* op = aout + (size_t)((b << 10) + row) * 4096 + h * 128;
#pragma unroll
      for (int n8 = 0; n8 < 8; ++n8)
        op[n8 * 16 + l16] = f2bf(o_acc[n8][r] * inv);
    }
  }
}

// ---------------------------------------------------------------------------
extern "C" void kernel_launch(void* const* d_in, const int* in_sizes, int n_in,
                              void* d_out, int out_size, void* d_ws,
                              size_t ws_size, hipStream_t stream) {
  const float* X = (const float*)d_in[0];      // [4096,4096]
  const float* Wqkv = (const float*)d_in[1];   // [6144,4096]
  const float* Wo = (const float*)d_in[2];     // [4096,4096]
  (void)in_sizes; (void)n_in; (void)out_size; (void)ws_size;

  char* ws = (char*)d_ws;
  unsigned short* Wqkvb = (unsigned short*)ws;
  unsigned short* AttnB = (unsigned short*)ws;             // reuse post-GEMM1
  unsigned short* Xb = (unsigned short*)(ws + 50331648);
  unsigned short* Wob = (unsigned short*)(ws + 50331648);  // reuse post-GEMM1
  unsigned short* QKVb = (unsigned short*)(ws + 83886080);

  cvt_f32_bf16<<<16384, 256, 0, stream>>>((const float4*)X, (u16x4*)Xb, 4194304);
  cvt_f32_bf16<<<24576, 256, 0, stream>>>((const float4*)Wqkv, (u16x4*)Wqkvb, 6291456);
  gemm_bt_w<1><<<dim3(24, 32), 256, 0, stream>>>(Xb, Wqkvb, QKVb, 4096, 6144, 4096);
  rope_k_kernel<<<dim3(4096, 2), 256, 0, stream>>>(QKVb);
  cvt_f32_bf16<<<16384, 256, 0, stream>>>((const float4*)Wo, (u16x4*)Wob, 4194304);
  flash_attn<<<dim3(8, 32, 4), 256, 0, stream>>>(QKVb, AttnB);
  gemm_bt_w<0><<<dim3(16, 32), 256, 0, stream>>>(AttnB, Wob, d_out, 4096, 4096, 4096);
}